// Round 1
// baseline (440.189 us; speedup 1.0000x reference)
//
#include <hip/hip_runtime.h>
#include <hip/hip_fp16.h>
#include <cstdint>
#include <cstddef>

// QLinear: per-token int8 quant -> int8 GEMM (MFMA 32x32x32 i8) -> dequant+bias
// M=8192, K=4096, N=4096.  weight_q arrives as int32 (harness promotes ints),
// bias fp16 promoted to fp32 (harness promotes non-bf16 floats), out as fp32.

#define MDIM 8192
#define KDIM 4096
#define NDIM 4096

typedef int v4i  __attribute__((ext_vector_type(4)));
typedef int v16i __attribute__((ext_vector_type(16)));

__device__ __forceinline__ void load_lds_16(const void* g, void* l) {
  __builtin_amdgcn_global_load_lds((const __attribute__((address_space(1))) void*)g,
                                   (__attribute__((address_space(3))) void*)l,
                                   16, 0, 0);
}

// ---------------- per-token quantization ----------------
// one block (256 thr) per row; thread t handles float4s at [t + 256*i], i<4
extern "C" __global__ __launch_bounds__(256)
void qlin_quant_x(const float* __restrict__ x, int8_t* __restrict__ xq,
                  float* __restrict__ xs) {
  const int row = blockIdx.x;
  const int t   = threadIdx.x;
  const float4* xr = (const float4*)(x + (size_t)row * KDIM);
  float4 v[4];
  float amax = 0.f;
#pragma unroll
  for (int i = 0; i < 4; ++i) {
    v[i] = xr[t + 256 * i];
    amax = fmaxf(amax, fmaxf(fmaxf(fabsf(v[i].x), fabsf(v[i].y)),
                             fmaxf(fabsf(v[i].z), fabsf(v[i].w))));
  }
#pragma unroll
  for (int off = 32; off > 0; off >>= 1)
    amax = fmaxf(amax, __shfl_xor(amax, off, 64));
  __shared__ float smax[4];
  if ((t & 63) == 0) smax[t >> 6] = amax;
  __syncthreads();
  amax = fmaxf(fmaxf(smax[0], smax[1]), fmaxf(smax[2], smax[3]));
  const float scale = fmaxf(amax, 1e-7f) / 127.0f;  // matches jnp exactly
  if (t == 0) xs[row] = scale;
  int* outp = (int*)(xq + (size_t)row * KDIM);
#pragma unroll
  for (int i = 0; i < 4; ++i) {
    // rintf = round-half-even = jnp.round; exact division matches x / x_scale
    int q0 = (int)rintf(v[i].x / scale);
    int q1 = (int)rintf(v[i].y / scale);
    int q2 = (int)rintf(v[i].z / scale);
    int q3 = (int)rintf(v[i].w / scale);
    q0 = min(127, max(-128, q0));
    q1 = min(127, max(-128, q1));
    q2 = min(127, max(-128, q2));
    q3 = min(127, max(-128, q3));
    outp[t + 256 * i] = (q0 & 0xff) | ((q1 & 0xff) << 8) |
                        ((q2 & 0xff) << 16) | ((q3 & 0xff) << 24);
  }
}

// ---------------- weight int32 -> int8 repack ----------------
extern "C" __global__ __launch_bounds__(256)
void qlin_pack_w(const int* __restrict__ w32, int8_t* __restrict__ w8) {
  const int idx = blockIdx.x * 256 + threadIdx.x;  // one per 4 elements
  const int4 w = ((const int4*)w32)[idx];
  ((int*)w8)[idx] = (w.x & 0xff) | ((w.y & 0xff) << 8) |
                    ((w.z & 0xff) << 16) | ((w.w & 0xff) << 24);
}

// ---------------- int8 GEMM, 128x128 tile, BK=64, mfma_i32_32x32x32_i8 ----
// 4 waves; wave (wr,wc) owns the 64x64 quadrant as 2x2 tiles of 32x32.
// A = xq [M,K] row-major; B = w8 [N,K] row-major (i.e. B^T — K-contiguous).
extern "C" __global__ __launch_bounds__(256)
void qlin_gemm(const int8_t* __restrict__ Aq, const int8_t* __restrict__ Bq,
               const float* __restrict__ xs, const float* __restrict__ ws,
               const float* __restrict__ bias, float* __restrict__ out) {
  __shared__ int8_t As[128 * 64];
  __shared__ int8_t Bs[128 * 64];
  const int tid  = threadIdx.x;
  const int lane = tid & 63;
  const int wave = tid >> 6;
  const int wr   = wave >> 1;
  const int wc   = wave & 1;
  const int m0   = blockIdx.y * 128;
  const int n0   = blockIdx.x * 128;

  // staging coords: thread tid loads 16B; LDS dest = base + tid*16 (wave-uniform
  // base + lane*16, as global_load_lds requires). Row = tid>>2, 16B-chunk = tid&3.
  const int srow = tid >> 2;
  const int scol = (tid & 3) * 16;

  const int8_t* Ab = Aq + (size_t)m0 * KDIM;
  const int8_t* Bb = Bq + (size_t)n0 * KDIM;

  v16i acc[2][2];
#pragma unroll
  for (int i = 0; i < 2; ++i)
#pragma unroll
    for (int j = 0; j < 2; ++j)
#pragma unroll
      for (int r = 0; r < 16; ++r) acc[i][j][r] = 0;

  const int r = lane & 31;
  const int g = (lane >> 5) * 16;  // byte offset of this lane's k-group

  for (int k0 = 0; k0 < KDIM; k0 += 64) {
    load_lds_16(Ab + (size_t)srow * KDIM + (k0 + scol), As + tid * 16);
    load_lds_16(Ab + (size_t)(srow + 64) * KDIM + (k0 + scol), As + 4096 + tid * 16);
    load_lds_16(Bb + (size_t)srow * KDIM + (k0 + scol), Bs + tid * 16);
    load_lds_16(Bb + (size_t)(srow + 64) * KDIM + (k0 + scol), Bs + 4096 + tid * 16);
    __builtin_amdgcn_s_waitcnt(0);
    __syncthreads();

#pragma unroll
    for (int ks = 0; ks < 2; ++ks) {
      v4i a[2], b[2];
#pragma unroll
      for (int i = 0; i < 2; ++i)
        a[i] = *(const v4i*)(As + (wr * 64 + i * 32 + r) * 64 + ks * 32 + g);
#pragma unroll
      for (int j = 0; j < 2; ++j)
        b[j] = *(const v4i*)(Bs + (wc * 64 + j * 32 + r) * 64 + ks * 32 + g);
#pragma unroll
      for (int i = 0; i < 2; ++i)
#pragma unroll
        for (int j = 0; j < 2; ++j)
          acc[i][j] = __builtin_amdgcn_mfma_i32_32x32x32_i8(a[i], b[j], acc[i][j], 0, 0, 0);
    }
    __syncthreads();
  }

  // epilogue: C/D layout col=lane&31, row=(reg&3)+8*(reg>>2)+4*(lane>>5)
  const int col = lane & 31;
  const int rb  = (lane >> 5) * 4;
#pragma unroll
  for (int j = 0; j < 2; ++j) {
    const int gc = n0 + wc * 64 + j * 32 + col;
    const float wsv = ws[gc];
    const float bv  = bias[gc];
#pragma unroll
    for (int i = 0; i < 2; ++i) {
      const int grb = m0 + wr * 64 + i * 32 + rb;
#pragma unroll
      for (int reg = 0; reg < 16; ++reg) {
        const int gr = grb + (reg & 3) + 8 * (reg >> 2);
        float t = (float)acc[i][j][reg] * xs[gr];  // (acc * x_scale)
        t = t * wsv + bv;                          // * w_scale + bias
        // reference casts to fp16; round through fp16 for bit-closeness
        out[(size_t)gr * NDIM + gc] = __half2float(__float2half(t));
      }
    }
  }
}

extern "C" void kernel_launch(void* const* d_in, const int* in_sizes, int n_in,
                              void* d_out, int out_size, void* d_ws, size_t ws_size,
                              hipStream_t stream) {
  const float* x      = (const float*)d_in[0];
  const int*   wq32   = (const int*)d_in[1];    // int8 promoted to int32 by harness
  const float* wscale = (const float*)d_in[2];
  const float* bias   = (const float*)d_in[3];  // fp16 promoted to fp32 by harness
  float*       out    = (float*)d_out;

  int8_t* xq = (int8_t*)d_ws;                                    // M*K   = 32 MiB
  int8_t* w8 = (int8_t*)d_ws + (size_t)MDIM * KDIM;              // N*K   = 16 MiB
  float*  xs = (float*)((int8_t*)d_ws + (size_t)MDIM * KDIM + (size_t)NDIM * KDIM);

  qlin_quant_x<<<MDIM, 256, 0, stream>>>(x, xq, xs);
  qlin_pack_w<<<(NDIM * KDIM / 4) / 256, 256, 0, stream>>>(wq32, w8);
  qlin_gemm<<<dim3(NDIM / 128, MDIM / 128), 256, 0, stream>>>(xq, w8, xs, wscale, bias, out);
}